// Round 5
// baseline (241.114 us; speedup 1.0000x reference)
//
#include <hip/hip_runtime.h>
#include <hip/hip_bf16.h>
#include <hip/hip_fp16.h>

// GCN 2-layer: z = relu(A(relu(A(xW1)+b1)W2)+b2), A = D^-1/2 (Adj+I) D^-1/2
// N=50000, E=800000, D=128. Output: float32.
// fp16 feature storage; XCD-partitioned CSR build to kill scatter write-amp.

#define NGRP 8          // one destination-range group per XCD
#define BPG  64         // blocks per group

__global__ void k_init(int* degi, int* cursor, int n) {
    int i = blockIdx.x * blockDim.x + threadIdx.x;
    if (i < n) { degi[i] = 0; cursor[i] = 0; }
}

// XCD-partitioned histogram: group g handles cols in [g*range, (g+1)*range)
__global__ __launch_bounds__(256) void k_hist(const int* __restrict__ col,
                                              int* degi, int E, int range) {
    const int g = blockIdx.x & (NGRP - 1);
    const int b = blockIdx.x >> 3;
    const int lo = g * range, hi = lo + range;
    for (int e = b * 256 + threadIdx.x; e < E; e += BPG * 256) {
        int c = col[e];
        if (c >= lo && c < hi) atomicAdd(&degi[c], 1);
    }
}

// local exclusive scan + per-block sums; also computes dinv = rsqrt(deg+1)
__global__ void k_scan_a(const int* __restrict__ degi, int* excl, int* partials,
                         float* dinv, int n) {
    __shared__ int s[256];
    int t = threadIdx.x;
    int i = blockIdx.x * 256 + t;
    int v = (i < n) ? degi[i] : 0;
    s[t] = v; __syncthreads();
    for (int o = 1; o < 256; o <<= 1) {
        int x = (t >= o) ? s[t - o] : 0;
        __syncthreads();
        s[t] += x;
        __syncthreads();
    }
    if (i < n) {
        excl[i] = s[t] - v;
        dinv[i] = rsqrtf((float)v + 1.0f);   // +1 self loop, never 0
    }
    if (t == 255) partials[blockIdx.x] = s[255];
}

__global__ void k_scan_b(int* partials, int nb) {
    __shared__ int s[256];
    int t = threadIdx.x;
    int v = (t < nb) ? partials[t] : 0;
    s[t] = v; __syncthreads();
    for (int o = 1; o < 256; o <<= 1) {
        int x = (t >= o) ? s[t - o] : 0;
        __syncthreads();
        s[t] += x;
        __syncthreads();
    }
    if (t < nb) partials[t] = s[t] - v;  // exclusive over blocks
}

// XCD-partitioned CSR fill: group writes only its own srcs/cursor range.
__global__ __launch_bounds__(256) void k_fill(const int* __restrict__ row,
                                              const int* __restrict__ col,
                                              const int* __restrict__ excl,
                                              const int* __restrict__ partials,
                                              int* cursor, int* srcs, int E, int range) {
    const int g = blockIdx.x & (NGRP - 1);
    const int b = blockIdx.x >> 3;
    const int lo = g * range, hi = lo + range;
    for (int e = b * 256 + threadIdx.x; e < E; e += BPG * 256) {
        int c = col[e];
        if (c >= lo && c < hi) {
            int p = excl[c] + partials[c >> 8] + atomicAdd(&cursor[c], 1);
            srcs[p] = row[e];
        }
    }
}

// --- C[M,128] = A[M,128] @ W[128,128], f32 accumulate, fp16 output ---
// block 256 thr, tile 64 rows x 128 cols, thread = 8 rows x 4 cols.
template <typename TIN>
__global__ __launch_bounds__(256) void k_gemm(const TIN* __restrict__ A,
                                              const float* __restrict__ W,
                                              __half* __restrict__ C, int M) {
    __shared__ float Xl[128][68];     // Xl[k][r] = A[row0+r][k]; pad 68 for banks
    const int t = threadIdx.x;
    const int row0 = blockIdx.x * 64;

    for (int c = t; c < 2048; c += 256) {
        int kq = c & 31, r = c >> 5;
        float4 v = make_float4(0.f, 0.f, 0.f, 0.f);
        int gr = row0 + r;
        if (gr < M) {
            if constexpr (sizeof(TIN) == 4) {
                v = ((const float4*)A)[gr * 32 + kq];
            } else {
                uint2 hp = ((const uint2*)A)[gr * 32 + kq];
                float2 a = __half22float2(*reinterpret_cast<__half2*>(&hp.x));
                float2 b = __half22float2(*reinterpret_cast<__half2*>(&hp.y));
                v = make_float4(a.x, a.y, b.x, b.y);
            }
        }
        Xl[4 * kq + 0][r] = v.x;
        Xl[4 * kq + 1][r] = v.y;
        Xl[4 * kq + 2][r] = v.z;
        Xl[4 * kq + 3][r] = v.w;
    }
    __syncthreads();

    const int cg = t & 31;   // cols 4*cg .. +4
    const int rg = t >> 5;   // rows 8*rg .. +8
    float acc[8][4];
#pragma unroll
    for (int i = 0; i < 8; i++)
#pragma unroll
        for (int j = 0; j < 4; j++) acc[i][j] = 0.f;

    const float4* Wv = (const float4*)W;
#pragma unroll 4
    for (int k = 0; k < 128; k++) {
        const float4 w  = Wv[(k << 5) + cg];              // W[k][4cg..4cg+3]
        const float4 xa = *(const float4*)(&Xl[k][rg << 3]);
        const float4 xb = *(const float4*)(&Xl[k][(rg << 3) + 4]);
        const float xs[8] = {xa.x, xa.y, xa.z, xa.w, xb.x, xb.y, xb.z, xb.w};
        const float ws4[4] = {w.x, w.y, w.z, w.w};
#pragma unroll
        for (int i = 0; i < 8; i++)
#pragma unroll
            for (int j = 0; j < 4; j++) acc[i][j] = fmaf(xs[i], ws4[j], acc[i][j]);
    }

#pragma unroll
    for (int i = 0; i < 8; i++) {
        int row = row0 + (rg << 3) + i;
        if (row < M) {
            __half2 p0 = __floats2half2_rn(acc[i][0], acc[i][1]);
            __half2 p1 = __floats2half2_rn(acc[i][2], acc[i][3]);
            uint2 pk;
            pk.x = *reinterpret_cast<unsigned*>(&p0);
            pk.y = *reinterpret_cast<unsigned*>(&p1);
            ((uint2*)C)[row * 32 + cg] = pk;   // 8B store, cols 4cg..4cg+3
        }
    }
}

// --- aggregation: out = relu(di*(sum_j dj*H[j] + di*H[i]) + b), H fp16 ---
// one wave per node; lane holds features (2*lane, 2*lane+1) as __half2.
__global__ __launch_bounds__(256) void k_agg(const __half* __restrict__ H,
                                             const int* __restrict__ srcs,
                                             const int* __restrict__ excl,
                                             const int* __restrict__ partials,
                                             const int* __restrict__ degi,
                                             const float* __restrict__ dinv,
                                             const float* __restrict__ bias,
                                             float* __restrict__ outF,
                                             __half* __restrict__ outH, int n) {
    int wave = threadIdx.x >> 6, lane = threadIdx.x & 63;
    int node = blockIdx.x * 4 + wave;
    if (node >= n) return;
    int s0 = excl[node] + partials[node >> 8];
    int d = degi[node];
    float di = dinv[node];
    const __half2* Hv = (const __half2*)H;

    float2 hv = __half22float2(Hv[(size_t)node * 64 + lane]);   // self term
    float ax = di * hv.x, ay = di * hv.y;

    for (int k = 0; k < d; k += 64) {
        int take = d - k; if (take > 64) take = 64;
        int idx = (lane < take) ? srcs[s0 + k + lane] : 0;
        float djl = (lane < take) ? dinv[idx] : 0.f;
        int u = 0;
        for (; u + 8 <= take; u += 8) {      // 8-deep MLP
            int jj[8]; float dd[8]; float2 vv[8];
#pragma unroll
            for (int q = 0; q < 8; q++) {
                jj[q] = __shfl(idx, u + q);
                dd[q] = __shfl(djl, u + q);
            }
#pragma unroll
            for (int q = 0; q < 8; q++) vv[q] = __half22float2(Hv[(size_t)jj[q] * 64 + lane]);
#pragma unroll
            for (int q = 0; q < 8; q++) {
                ax = fmaf(dd[q], vv[q].x, ax);
                ay = fmaf(dd[q], vv[q].y, ay);
            }
        }
        for (; u < take; u++) {
            int j = __shfl(idx, u);
            float dj = __shfl(djl, u);
            float2 v = __half22float2(Hv[(size_t)j * 64 + lane]);
            ax = fmaf(dj, v.x, ax); ay = fmaf(dj, v.y, ay);
        }
    }
    float2 b2 = ((const float2*)bias)[lane];
    float ox = fmaxf(fmaf(di, ax, b2.x), 0.f);
    float oy = fmaxf(fmaf(di, ay, b2.y), 0.f);
    if (outF) {
        ((float2*)outF)[(size_t)node * 64 + lane] = make_float2(ox, oy);
    } else {
        __half2 p = __floats2half2_rn(ox, oy);
        ((__half2*)outH)[(size_t)node * 64 + lane] = p;
    }
}

extern "C" void kernel_launch(void* const* d_in, const int* in_sizes, int n_in,
                              void* d_out, int out_size, void* d_ws, size_t ws_size,
                              hipStream_t stream) {
    const float* x  = (const float*)d_in[0];
    const int*   ei = (const int*)d_in[1];
    const float* W1 = (const float*)d_in[2];
    const float* b1 = (const float*)d_in[3];
    const float* W2 = (const float*)d_in[4];
    const float* b2 = (const float*)d_in[5];
    const int N = in_sizes[0] / 128;
    const int E = in_sizes[1] / 2;
    const int range = (N + NGRP - 1) / NGRP;

    char* w = (char*)d_ws;
    auto alloc = [&](size_t bytes) -> void* {
        void* p = (void*)w;
        w += (bytes + 255) & ~(size_t)255;
        return p;
    };
    int*    degi     = (int*)alloc((size_t)N * 4);
    int*    cursor   = (int*)alloc((size_t)N * 4);
    float*  dinv     = (float*)alloc((size_t)N * 4);
    int*    excl     = (int*)alloc((size_t)N * 4);
    int*    partials = (int*)alloc(1024);
    int*    srcs     = (int*)alloc((size_t)E * 4);
    __half* H        = (__half*)alloc((size_t)N * 128 * 2);
    __half* Z        = (__half*)alloc((size_t)N * 128 * 2);

    const int* rowp = ei;
    const int* colp = ei + E;
    const int nbN = (N + 255) / 256;

    k_init<<<nbN, 256, 0, stream>>>(degi, cursor, N);
    k_hist<<<NGRP * BPG, 256, 0, stream>>>(colp, degi, E, range);
    k_scan_a<<<nbN, 256, 0, stream>>>(degi, excl, partials, dinv, N);
    k_scan_b<<<1, 256, 0, stream>>>(partials, nbN);
    k_fill<<<NGRP * BPG, 256, 0, stream>>>(rowp, colp, excl, partials, cursor, srcs, E, range);

    k_gemm<float><<<(N + 63) / 64, 256, 0, stream>>>(x, W1, H, N);
    k_agg<<<(N + 3) / 4, 256, 0, stream>>>(H, srcs, excl, partials, degi, dinv, b1,
                                           nullptr, Z, N);
    k_gemm<__half><<<(N + 63) / 64, 256, 0, stream>>>(Z, W2, H, N);
    k_agg<<<(N + 3) / 4, 256, 0, stream>>>(H, srcs, excl, partials, degi, dinv, b2,
                                           (float*)d_out, nullptr, N);
}

// Round 6
// 202.604 us; speedup vs baseline: 1.1901x; 1.1901x over previous
//
#include <hip/hip_runtime.h>
#include <hip/hip_bf16.h>
#include <hip/hip_fp16.h>

// GCN 2-layer: z = relu(A(relu(A(xW1)+b1)W2)+b2), A = D^-1/2 (Adj+I) D^-1/2
// N=50000, E=800000, D=128. Output: float32.
// CSR built via 2-level counting sort (LDS hist, no per-node global atomics).

#define BK 128                      // nodes per bucket
#define PACK_ROWBITS 20             // row in bits [0,20), colLocal in [20,27)

__global__ void k_zero(int* bcnt, int* gcur, int nb) {
    for (int i = threadIdx.x; i < nb; i += 256) { bcnt[i] = 0; gcur[i] = 0; }
}

// per-block LDS bucket histogram -> global bcnt
__global__ __launch_bounds__(256) void k_bhist(const int* __restrict__ col,
                                               int* bcnt, int E, int nb) {
    __shared__ int h[512];
    for (int i = threadIdx.x; i < nb; i += 256) h[i] = 0;
    __syncthreads();
    for (int e = blockIdx.x * 256 + threadIdx.x; e < E; e += gridDim.x * 256)
        atomicAdd(&h[col[e] >> 7], 1);
    __syncthreads();
    for (int i = threadIdx.x; i < nb; i += 256)
        if (h[i]) atomicAdd(&bcnt[i], h[i]);
}

// exclusive scan of bcnt[nb] -> bstart[nb+1]  (single block, 512 thr)
__global__ __launch_bounds__(512) void k_bscan(const int* __restrict__ bcnt,
                                               int* bstart, int nb, int E) {
    __shared__ int s[512];
    int t = threadIdx.x;
    int v = (t < nb) ? bcnt[t] : 0;
    s[t] = v; __syncthreads();
    for (int o = 1; o < 512; o <<= 1) {
        int x = (t >= o) ? s[t - o] : 0;
        __syncthreads();
        s[t] += x;
        __syncthreads();
    }
    if (t < nb) bstart[t] = s[t] - v;
    if (t == 0) bstart[nb] = E;
}

// scatter packed entries into bucket regions; block owns a contiguous edge chunk
__global__ __launch_bounds__(256) void k_bscatter(const int* __restrict__ row,
                                                  const int* __restrict__ col,
                                                  const int* __restrict__ bstart,
                                                  int* gcur, unsigned* ebuf,
                                                  int E, int nb, int chunk) {
    __shared__ int h[512];
    __shared__ int base[512];
    const int t = threadIdx.x;
    const int e0 = blockIdx.x * chunk;
    const int e1 = min(e0 + chunk, E);
    for (int i = t; i < nb; i += 256) h[i] = 0;
    __syncthreads();
    for (int e = e0 + t; e < e1; e += 256) atomicAdd(&h[col[e] >> 7], 1);
    __syncthreads();
    for (int i = t; i < nb; i += 256) {
        base[i] = h[i] ? atomicAdd(&gcur[i], h[i]) : 0;
        h[i] = 0;                                   // reuse as local cursor
    }
    __syncthreads();
    for (int e = e0 + t; e < e1; e += 256) {
        int c = col[e];
        int b = c >> 7;
        int loc = atomicAdd(&h[b], 1);
        ebuf[bstart[b] + base[b] + loc] =
            (unsigned)row[e] | ((unsigned)(c & (BK - 1)) << PACK_ROWBITS);
    }
}

// per-bucket node degree + dinv (LDS hist, coalesced writes, no global atomics)
__global__ __launch_bounds__(256) void k_bnode(const unsigned* __restrict__ ebuf,
                                               const int* __restrict__ bstart,
                                               int* degi, float* dinv, int N) {
    __shared__ int h[BK];
    const int t = threadIdx.x, b = blockIdx.x;
    if (t < BK) h[t] = 0;
    __syncthreads();
    const int s = bstart[b], cnt = bstart[b + 1] - s;
    for (int i = t; i < cnt; i += 256)
        atomicAdd(&h[(ebuf[s + i] >> PACK_ROWBITS) & (BK - 1)], 1);
    __syncthreads();
    int node = b * BK + t;
    if (t < BK && node < N) {
        degi[node] = h[t];
        dinv[node] = rsqrtf((float)h[t] + 1.0f);    // +1 self loop
    }
}

// node-level exclusive scan (2 kernels), startv = excl + partials[node>>8]
__global__ void k_scan_a(const int* __restrict__ degi, int* excl, int* partials, int n) {
    __shared__ int s[256];
    int t = threadIdx.x;
    int i = blockIdx.x * 256 + t;
    int v = (i < n) ? degi[i] : 0;
    s[t] = v; __syncthreads();
    for (int o = 1; o < 256; o <<= 1) {
        int x = (t >= o) ? s[t - o] : 0;
        __syncthreads();
        s[t] += x;
        __syncthreads();
    }
    if (i < n) excl[i] = s[t] - v;
    if (t == 255) partials[blockIdx.x] = s[255];
}

__global__ void k_scan_b(int* partials, int nb) {
    __shared__ int s[256];
    int t = threadIdx.x;
    int v = (t < nb) ? partials[t] : 0;
    s[t] = v; __syncthreads();
    for (int o = 1; o < 256; o <<= 1) {
        int x = (t >= o) ? s[t - o] : 0;
        __syncthreads();
        s[t] += x;
        __syncthreads();
    }
    if (t < nb) partials[t] = s[t] - v;
}

// per-bucket node-level CSR fill: LDS cursors, single-owner coalesced srcs region
__global__ __launch_bounds__(256) void k_bfill(const unsigned* __restrict__ ebuf,
                                               const int* __restrict__ bstart,
                                               const int* __restrict__ excl,
                                               const int* __restrict__ partials,
                                               int* srcs) {
    __shared__ int cur[BK];
    const int t = threadIdx.x, b = blockIdx.x;
    if (t < BK) cur[t] = 0;
    __syncthreads();
    const int s = bstart[b], cnt = bstart[b + 1] - s;
    const int n0 = b * BK;
    for (int i = t; i < cnt; i += 256) {
        unsigned u = ebuf[s + i];
        int c = (u >> PACK_ROWBITS) & (BK - 1);
        int node = n0 + c;
        int loc = atomicAdd(&cur[c], 1);
        srcs[excl[node] + partials[node >> 8] + loc] = (int)(u & ((1u << PACK_ROWBITS) - 1));
    }
}

// --- C[M,128] = A[M,128] @ W[128,128], f32 accumulate, fp16 output ---
template <typename TIN>
__global__ __launch_bounds__(256) void k_gemm(const TIN* __restrict__ A,
                                              const float* __restrict__ W,
                                              __half* __restrict__ C, int M) {
    __shared__ float Xl[128][68];
    const int t = threadIdx.x;
    const int row0 = blockIdx.x * 64;

    for (int c = t; c < 2048; c += 256) {
        int kq = c & 31, r = c >> 5;
        float4 v = make_float4(0.f, 0.f, 0.f, 0.f);
        int gr = row0 + r;
        if (gr < M) {
            if constexpr (sizeof(TIN) == 4) {
                v = ((const float4*)A)[gr * 32 + kq];
            } else {
                uint2 hp = ((const uint2*)A)[gr * 32 + kq];
                float2 a = __half22float2(*reinterpret_cast<__half2*>(&hp.x));
                float2 b = __half22float2(*reinterpret_cast<__half2*>(&hp.y));
                v = make_float4(a.x, a.y, b.x, b.y);
            }
        }
        Xl[4 * kq + 0][r] = v.x;
        Xl[4 * kq + 1][r] = v.y;
        Xl[4 * kq + 2][r] = v.z;
        Xl[4 * kq + 3][r] = v.w;
    }
    __syncthreads();

    const int cg = t & 31;
    const int rg = t >> 5;
    float acc[8][4];
#pragma unroll
    for (int i = 0; i < 8; i++)
#pragma unroll
        for (int j = 0; j < 4; j++) acc[i][j] = 0.f;

    const float4* Wv = (const float4*)W;
#pragma unroll 4
    for (int k = 0; k < 128; k++) {
        const float4 w  = Wv[(k << 5) + cg];
        const float4 xa = *(const float4*)(&Xl[k][rg << 3]);
        const float4 xb = *(const float4*)(&Xl[k][(rg << 3) + 4]);
        const float xs[8] = {xa.x, xa.y, xa.z, xa.w, xb.x, xb.y, xb.z, xb.w};
        const float ws4[4] = {w.x, w.y, w.z, w.w};
#pragma unroll
        for (int i = 0; i < 8; i++)
#pragma unroll
            for (int j = 0; j < 4; j++) acc[i][j] = fmaf(xs[i], ws4[j], acc[i][j]);
    }

#pragma unroll
    for (int i = 0; i < 8; i++) {
        int row = row0 + (rg << 3) + i;
        if (row < M) {
            __half2 p0 = __floats2half2_rn(acc[i][0], acc[i][1]);
            __half2 p1 = __floats2half2_rn(acc[i][2], acc[i][3]);
            uint2 pk;
            pk.x = *reinterpret_cast<unsigned*>(&p0);
            pk.y = *reinterpret_cast<unsigned*>(&p1);
            ((uint2*)C)[row * 32 + cg] = pk;
        }
    }
}

// --- aggregation: out = relu(di*(sum_j dj*H[j] + di*H[i]) + b), H fp16 ---
__global__ __launch_bounds__(256) void k_agg(const __half* __restrict__ H,
                                             const int* __restrict__ srcs,
                                             const int* __restrict__ excl,
                                             const int* __restrict__ partials,
                                             const int* __restrict__ degi,
                                             const float* __restrict__ dinv,
                                             const float* __restrict__ bias,
                                             float* __restrict__ outF,
                                             __half* __restrict__ outH, int n) {
    int wave = threadIdx.x >> 6, lane = threadIdx.x & 63;
    int node = blockIdx.x * 4 + wave;
    if (node >= n) return;
    int s0 = excl[node] + partials[node >> 8];
    int d = degi[node];
    float di = dinv[node];
    const __half2* Hv = (const __half2*)H;

    float2 hv = __half22float2(Hv[(size_t)node * 64 + lane]);
    float ax = di * hv.x, ay = di * hv.y;

    for (int k = 0; k < d; k += 64) {
        int take = d - k; if (take > 64) take = 64;
        int idx = (lane < take) ? srcs[s0 + k + lane] : 0;
        float djl = (lane < take) ? dinv[idx] : 0.f;
        int u = 0;
        for (; u + 8 <= take; u += 8) {
            int jj[8]; float dd[8]; float2 vv[8];
#pragma unroll
            for (int q = 0; q < 8; q++) {
                jj[q] = __shfl(idx, u + q);
                dd[q] = __shfl(djl, u + q);
            }
#pragma unroll
            for (int q = 0; q < 8; q++) vv[q] = __half22float2(Hv[(size_t)jj[q] * 64 + lane]);
#pragma unroll
            for (int q = 0; q < 8; q++) {
                ax = fmaf(dd[q], vv[q].x, ax);
                ay = fmaf(dd[q], vv[q].y, ay);
            }
        }
        for (; u < take; u++) {
            int j = __shfl(idx, u);
            float dj = __shfl(djl, u);
            float2 v = __half22float2(Hv[(size_t)j * 64 + lane]);
            ax = fmaf(dj, v.x, ax); ay = fmaf(dj, v.y, ay);
        }
    }
    float2 b2 = ((const float2*)bias)[lane];
    float ox = fmaxf(fmaf(di, ax, b2.x), 0.f);
    float oy = fmaxf(fmaf(di, ay, b2.y), 0.f);
    if (outF) {
        ((float2*)outF)[(size_t)node * 64 + lane] = make_float2(ox, oy);
    } else {
        __half2 p = __floats2half2_rn(ox, oy);
        ((__half2*)outH)[(size_t)node * 64 + lane] = p;
    }
}

extern "C" void kernel_launch(void* const* d_in, const int* in_sizes, int n_in,
                              void* d_out, int out_size, void* d_ws, size_t ws_size,
                              hipStream_t stream) {
    const float* x  = (const float*)d_in[0];
    const int*   ei = (const int*)d_in[1];
    const float* W1 = (const float*)d_in[2];
    const float* b1 = (const float*)d_in[3];
    const float* W2 = (const float*)d_in[4];
    const float* b2 = (const float*)d_in[5];
    const int N = in_sizes[0] / 128;
    const int E = in_sizes[1] / 2;
    const int NB = (N + BK - 1) / BK;       // 391 buckets

    char* w = (char*)d_ws;
    auto alloc = [&](size_t bytes) -> void* {
        void* p = (void*)w;
        w += (bytes + 255) & ~(size_t)255;
        return p;
    };
    int*      degi     = (int*)alloc((size_t)N * 4);
    float*    dinv     = (float*)alloc((size_t)N * 4);
    int*      excl     = (int*)alloc((size_t)N * 4);
    int*      partials = (int*)alloc(1024);
    int*      bcnt     = (int*)alloc((size_t)(NB + 1) * 4);
    int*      bstart   = (int*)alloc((size_t)(NB + 1) * 4);
    int*      gcur     = (int*)alloc((size_t)NB * 4);
    unsigned* ebuf     = (unsigned*)alloc((size_t)E * 4);
    int*      srcs     = (int*)alloc((size_t)E * 4);
    __half*   H        = (__half*)alloc((size_t)N * 128 * 2);
    __half*   Z        = (__half*)alloc((size_t)N * 128 * 2);

    const int* rowp = ei;
    const int* colp = ei + E;
    const int nbN = (N + 255) / 256;
    const int chunk = 8192;
    const int nScatter = (E + chunk - 1) / chunk;

    k_zero<<<1, 256, 0, stream>>>(bcnt, gcur, NB);
    k_bhist<<<128, 256, 0, stream>>>(colp, bcnt, E, NB);
    k_bscan<<<1, 512, 0, stream>>>(bcnt, bstart, NB, E);
    k_bscatter<<<nScatter, 256, 0, stream>>>(rowp, colp, bstart, gcur, ebuf, E, NB, chunk);
    k_bnode<<<NB, 256, 0, stream>>>(ebuf, bstart, degi, dinv, N);
    k_scan_a<<<nbN, 256, 0, stream>>>(degi, excl, partials, N);
    k_scan_b<<<1, 256, 0, stream>>>(partials, nbN);
    k_bfill<<<NB, 256, 0, stream>>>(ebuf, bstart, excl, partials, srcs);

    k_gemm<float><<<(N + 63) / 64, 256, 0, stream>>>(x, W1, H, N);
    k_agg<<<(N + 3) / 4, 256, 0, stream>>>(H, srcs, excl, partials, degi, dinv, b1,
                                           nullptr, Z, N);
    k_gemm<__half><<<(N + 63) / 64, 256, 0, stream>>>(Z, W2, H, N);
    k_agg<<<(N + 3) / 4, 256, 0, stream>>>(H, srcs, excl, partials, degi, dinv, b2,
                                           (float*)d_out, nullptr, N);
}